// Round 10
// baseline (640.983 us; speedup 1.0000x reference)
//
#include <hip/hip_runtime.h>

#define T_TOK 2048
#define HD    2048
#define NE    32
#define ID    768
#define TOPK  8
#define NPAIR (T_TOK * TOPK)
#define MAXT  160                            // max padded tiles: NPAIR/128 + NE

typedef short bf16x8 __attribute__((ext_vector_type(8)));
typedef short bf16x4 __attribute__((ext_vector_type(4)));
typedef float f32x4  __attribute__((ext_vector_type(4)));

__device__ inline unsigned short f2bf(float f) {
    unsigned u = __builtin_bit_cast(unsigned, f);
    u += 0x7FFF + ((u >> 16) & 1);          // round-to-nearest-even
    return (unsigned short)(u >> 16);
}
__device__ inline unsigned pk2(float a, float b) {
    return (unsigned)f2bf(a) | ((unsigned)f2bf(b) << 16);
}

__device__ inline void gload16(const void* g, void* l) {
    __builtin_amdgcn_global_load_lds(
        (const __attribute__((address_space(1))) unsigned*)g,
        (__attribute__((address_space(3))) unsigned*)l, 16, 0, 0);
}

// LDS byte offset (AS3 32-bit), NOT truncated generic/flat address
#define LDS_U32(p) ((unsigned)(uintptr_t)(__attribute__((address_space(3))) const void*)(const void*)(p))

// hardware transpose-read: per-lane 64b load + intra-16-lane permutation
// out[l][j] = in[(l15>>2)+j*4][l15&3]; canonical packed use: addr_l = subtile_base + l15*8
#define TR0(d, a) asm volatile("ds_read_b64_tr_b16 %0, %1"              : "=v"(d) : "v"(a))
#define TR1(d, a) asm volatile("ds_read_b64_tr_b16 %0, %1 offset:1024"  : "=v"(d) : "v"(a))
#define TR2(d, a) asm volatile("ds_read_b64_tr_b16 %0, %1 offset:2048"  : "=v"(d) : "v"(a))

// ================= prep: pure streaming fp32->bf16 cvt (layout-preserving) + router =================
#define CVT_WBLK 12288                       // NE*HD*ID/(256*16)
#define CVT_XBLK 1024                        // T_TOK*HD/(256*16)
#define PREP_GRID (3 * CVT_WBLK + CVT_XBLK + T_TOK)

__global__ __launch_bounds__(256)
void prep_cvt(const float* __restrict__ x, const float* __restrict__ wg,
              const float* __restrict__ wgp, const float* __restrict__ wup,
              const float* __restrict__ wdp,
              unsigned short* __restrict__ X16, unsigned short* __restrict__ WG16,
              unsigned short* __restrict__ WU16, unsigned short* __restrict__ WD16,
              int* __restrict__ topk_idx, float* __restrict__ topk_w,
              int* __restrict__ counts) {
    int bid = blockIdx.x;
    if (bid < 3 * CVT_WBLK + CVT_XBLK) {     // streaming cvt: 16 f32 -> 16 bf16 per thread
        const float* src; unsigned short* dst;
        if (bid < CVT_WBLK)              { src = wgp; dst = WG16; }
        else if (bid < 2 * CVT_WBLK)     { src = wup; dst = WU16; bid -= CVT_WBLK; }
        else if (bid < 3 * CVT_WBLK)     { src = wdp; dst = WD16; bid -= 2 * CVT_WBLK; }
        else                             { src = x;   dst = X16;  bid -= 3 * CVT_WBLK; }
        size_t base = ((size_t)bid * 256 + threadIdx.x) * 16;
        const float4* s = (const float4*)(src + base);
        float4 f0 = s[0], f1 = s[1], f2 = s[2], f3 = s[3];
        uint4 o0, o1;
        o0.x = pk2(f0.x, f0.y); o0.y = pk2(f0.z, f0.w);
        o0.z = pk2(f1.x, f1.y); o0.w = pk2(f1.z, f1.w);
        o1.x = pk2(f2.x, f2.y); o1.y = pk2(f2.z, f2.w);
        o1.z = pk2(f3.x, f3.y); o1.w = pk2(f3.z, f3.w);
        *(uint4*)(dst + base)     = o0;
        *(uint4*)(dst + base + 8) = o1;
        return;
    }
    // router: one block per token
    int t = bid - (3 * CVT_WBLK + CVT_XBLK);
    int tid = threadIdx.x;
    int e = tid & 31, seg = tid >> 5;
    const float* xr = x + (size_t)t * HD + seg * 256;
    const float* wp = wg + (size_t)(seg * 256) * NE + e;
    float acc = 0.f;
    #pragma unroll 4
    for (int j = 0; j < 256; ++j) acc += xr[j] * wp[j * NE];
    __shared__ float part[8][33];
    __shared__ float lg[32];
    part[seg][e] = acc;
    __syncthreads();
    if (tid < 32) {
        float s = 0.f;
        #pragma unroll
        for (int g = 0; g < 8; ++g) s += part[g][tid];
        lg[tid] = s;
    }
    __syncthreads();
    if (tid == 0) {
        float m = lg[0];
        for (int i = 1; i < 32; ++i) m = fmaxf(m, lg[i]);
        for (int i = 0; i < 32; ++i) lg[i] = __expf(lg[i] - m);
        int   idxs[TOPK]; float wv[TOPK]; float wsum = 0.f;
        #pragma unroll
        for (int k = 0; k < TOPK; ++k) {
            float best = -1.f; int bi = 0;
            for (int i = 0; i < 32; ++i) if (lg[i] > best) { best = lg[i]; bi = i; }
            idxs[k] = bi; wv[k] = best; wsum += best; lg[bi] = -1.f;
        }
        #pragma unroll
        for (int k = 0; k < TOPK; ++k) {
            topk_idx[t * TOPK + k] = idxs[k];
            topk_w[t * TOPK + k]   = wv[k] / wsum;
            atomicAdd(&counts[idxs[k]], 1);
        }
    }
}

// ---------------- build padded tile table ----------------
__global__ void build_tiles(const int* __restrict__ counts, int* __restrict__ cursor,
                            int* __restrict__ tE, int* __restrict__ tStart,
                            int* __restrict__ tCnt) {
    if (threadIdx.x == 0 && blockIdx.x == 0) {
        int run = 0, nt = 0;
        for (int e = 0; e < NE; ++e) {
            cursor[e] = run;
            int c = counts[e];
            int nte = (c + 127) >> 7;
            for (int j = 0; j < nte; ++j) {
                tE[nt] = e;
                tStart[nt] = run + j * 128;
                tCnt[nt] = (c - j * 128 < 128) ? (c - j * 128) : 128;
                ++nt;
            }
            run += nte * 128;
        }
        for (; nt < MAXT; ++nt) { tE[nt] = -1; tStart[nt] = 0; tCnt[nt] = 0; }
    }
}

__global__ void scatter_kernel(const int* __restrict__ topk_idx, int* __restrict__ cursor,
                               int* __restrict__ token_list) {
    int i = blockIdx.x * 256 + threadIdx.x;
    int e = topk_idx[i];
    int pos = atomicAdd(&cursor[e], 1);
    token_list[pos] = i;
}

// ================= GEMM1: act = silu(X Wg) * (X Wu); B [k][n] row-major, packed tr-subtiles =================
// B LDS: 128 subtiles (kb 0..15 major, nbb 0..7) of 4k x 16n packed at byte s*128.
// Staging instr q: subtile s = q*8+(l>>3); lane sources row kb*4+((l&7)>>1), col nbb*16+(l&7&1)*8.
// Fragment (ks,nf,wn): subtile idx = (ks*8+2*lhi)*8 + wn*4+nf; addr = idx*128 + l15*8; hi kb via offset:1024.
__global__ __launch_bounds__(256, 2)
void gemm1_kernel(const unsigned short* __restrict__ X16,
                  const unsigned short* __restrict__ WG, const unsigned short* __restrict__ WU,
                  const int* __restrict__ token_list,
                  const int* __restrict__ tE, const int* __restrict__ tStart,
                  const int* __restrict__ tCnt, unsigned short* __restrict__ act16) {
    int tile = blockIdx.x / 6, it = blockIdx.x % 6;
    int e = tE[tile];
    if (e < 0) return;
    int start = tStart[tile], cnt = tCnt[tile];
    int i0 = it * 128;

    __shared__ __align__(16) unsigned short As[128 * 64];   // A: XOR-swizzled rows (proven R8)
    __shared__ __align__(16) unsigned short Bg[64 * 128];   // packed tr-subtiled
    __shared__ __align__(16) unsigned short Bu[64 * 128];
    __shared__ int rowTok[128];

    int tid = threadIdx.x;
    if (tid < 128)
        rowTok[tid] = (tid < cnt) ? (token_list[start + tid] >> 3) : 0;
    __syncthreads();

    int lane = tid & 63, w = tid >> 6;
    int sub = lane & 7, lrow = lane >> 3, l7 = lane & 7;

    const unsigned short* aP[4]; const unsigned short* gP[4]; const unsigned short* uP[4];
    #pragma unroll
    for (int c = 0; c < 4; ++c) {
        int q = w * 4 + c;
        int r = q * 8 + lrow;
        aP[c] = X16 + (size_t)rowTok[r] * HD + (sub ^ (r & 7)) * 8;
        int s = q * 8 + (lane >> 3);         // kb = s>>3 (= q), nbb = s&7
        size_t ro = ((size_t)e * HD + (s >> 3) * 4 + (l7 >> 1)) * ID
                  + i0 + (s & 7) * 16 + (l7 & 1) * 8;
        gP[c] = WG + ro;
        uP[c] = WU + ro;
    }

    f32x4 accg[4][4], accu[4][4];
    #pragma unroll
    for (int m = 0; m < 4; ++m)
        #pragma unroll
        for (int n = 0; n < 4; ++n) {
            f32x4 z = {0.f, 0.f, 0.f, 0.f};
            accg[m][n] = z; accu[m][n] = z;
        }

    int wm = w >> 1, wn = w & 1, l15 = lane & 15, lhi = lane >> 4;
    const bf16x8* Af = (const bf16x8*)As;
    unsigned bgBase = LDS_U32(Bg) + lhi * 2048 + wn * 512 + l15 * 8;
    unsigned buBase = LDS_U32(Bu) + lhi * 2048 + wn * 512 + l15 * 8;

    for (int k0 = 0; k0 < HD; k0 += 64) {
        #pragma unroll
        for (int c = 0; c < 4; ++c) {
            int q = w * 4 + c;
            gload16(aP[c] + k0, (char*)As + q * 1024);
            gload16(gP[c] + (size_t)k0 * ID, (char*)Bg + q * 1024);
            gload16(uP[c] + (size_t)k0 * ID, (char*)Bu + q * 1024);
        }
        __syncthreads();
        #pragma unroll
        for (int ks = 0; ks < 2; ++ks) {
            int cc = ks * 4 + lhi;
            bf16x8 a[4];
            #pragma unroll
            for (int m = 0; m < 4; ++m) { int r = wm * 64 + m * 16 + l15; a[m] = Af[r * 8 + (cc ^ (r & 7))]; }
            bf16x4 gl[4], gh[4], ul[4], uh[4];
            #pragma unroll
            for (int n = 0; n < 4; ++n) {
                unsigned adG = bgBase + ks * 8192 + n * 128;
                unsigned adU = buBase + ks * 8192 + n * 128;
                TR0(gl[n], adG); TR1(gh[n], adG);
                TR0(ul[n], adU); TR1(uh[n], adU);
            }
            asm volatile("s_waitcnt lgkmcnt(0)" ::: "memory");
            __builtin_amdgcn_sched_barrier(0);
            #pragma unroll
            for (int m = 0; m < 4; ++m)
                #pragma unroll
                for (int n = 0; n < 4; ++n) {
                    bf16x8 bg = __builtin_shufflevector(gl[n], gh[n], 0, 1, 2, 3, 4, 5, 6, 7);
                    bf16x8 bu = __builtin_shufflevector(ul[n], uh[n], 0, 1, 2, 3, 4, 5, 6, 7);
                    accg[m][n] = __builtin_amdgcn_mfma_f32_16x16x32_bf16(a[m], bg, accg[m][n], 0, 0, 0);
                    accu[m][n] = __builtin_amdgcn_mfma_f32_16x16x32_bf16(a[m], bu, accu[m][n], 0, 0, 0);
                }
        }
        __syncthreads();
    }

    #pragma unroll
    for (int m = 0; m < 4; ++m) {
        int rb = wm * 64 + m * 16 + lhi * 4;
        #pragma unroll
        for (int q = 0; q < 4; ++q) {
            int r = rb + q;
            size_t orow = (size_t)(start + r) * ID + i0 + wn * 64;
            #pragma unroll
            for (int n = 0; n < 4; ++n) {
                float g = accg[m][n][q], uu = accu[m][n][q];
                float a = g / (1.f + __expf(-g)) * uu;
                act16[orow + n * 16 + l15] = f2bf(a);
            }
        }
    }
}

// ================= GEMM2: out += w * (act Wd); B = WD [k=i][n=h], packed tr-subtiles =================
// B LDS: 256 subtiles (kb 0..15 major, nbb 0..15) at byte s*128.
// Staging instr q (8/wave): s = q*8+(l>>3); kb = s>>4, nbb = s&15.
// Fragment: subtile idx = (ks*8+2*lhi)*16 + wn*8+nf; hi kb via offset:2048.
__global__ __launch_bounds__(256, 2)
void gemm2_kernel(const unsigned short* __restrict__ act16, const unsigned short* __restrict__ WD,
                  const int* __restrict__ token_list,
                  const int* __restrict__ tE, const int* __restrict__ tStart,
                  const int* __restrict__ tCnt, const float* __restrict__ topk_w,
                  float* __restrict__ out) {
    int tile = blockIdx.x / 8, ht = blockIdx.x % 8;
    int e = tE[tile];
    if (e < 0) return;
    int start = tStart[tile], cnt = tCnt[tile];
    int h0 = ht * 256;

    __shared__ __align__(16) unsigned short As[128 * 64];
    __shared__ __align__(16) unsigned short Bs[64 * 256];
    __shared__ int   rowTok[128];
    __shared__ float rowW[128];

    int tid = threadIdx.x;
    if (tid < 128) {
        if (tid < cnt) { int v = token_list[start + tid]; rowTok[tid] = v >> 3; rowW[tid] = topk_w[v]; }
        else           { rowTok[tid] = 0;                 rowW[tid] = 0.f; }
    }
    __syncthreads();

    int lane = tid & 63, w = tid >> 6;
    int sub = lane & 7, lrow = lane >> 3, l7 = lane & 7;

    const unsigned short* aP[4]; const unsigned short* bP[8];
    #pragma unroll
    for (int c = 0; c < 4; ++c) {
        int q = w * 4 + c;
        int r = q * 8 + lrow;
        aP[c] = act16 + (size_t)(start + r) * ID + (sub ^ (r & 7)) * 8;
    }
    #pragma unroll
    for (int c = 0; c < 8; ++c) {
        int q = w * 8 + c;
        int s = q * 8 + (lane >> 3);         // kb = s>>4, nbb = s&15
        bP[c] = WD + ((size_t)e * ID + (s >> 4) * 4 + (l7 >> 1)) * HD
                   + h0 + (s & 15) * 16 + (l7 & 1) * 8;
    }

    f32x4 acc[4][8];
    #pragma unroll
    for (int m = 0; m < 4; ++m)
        #pragma unroll
        for (int n = 0; n < 8; ++n) { f32x4 z = {0.f, 0.f, 0.f, 0.f}; acc[m][n] = z; }

    int wm = w >> 1, wn = w & 1, l15 = lane & 15, lhi = lane >> 4;
    const bf16x8* Af = (const bf16x8*)As;
    unsigned bBase = LDS_U32(Bs) + lhi * 4096 + wn * 1024 + l15 * 8;

    for (int k0 = 0; k0 < ID; k0 += 64) {
        #pragma unroll
        for (int c = 0; c < 4; ++c) {
            int q = w * 4 + c;
            gload16(aP[c] + k0, (char*)As + q * 1024);
        }
        #pragma unroll
        for (int c = 0; c < 8; ++c) {
            int q = w * 8 + c;
            gload16(bP[c] + (size_t)k0 * HD, (char*)Bs + q * 1024);
        }
        __syncthreads();
        #pragma unroll
        for (int ks = 0; ks < 2; ++ks) {
            int cc = ks * 4 + lhi;
            bf16x8 a[4];
            #pragma unroll
            for (int m = 0; m < 4; ++m) { int r = wm * 64 + m * 16 + l15; a[m] = Af[r * 8 + (cc ^ (r & 7))]; }
            bf16x4 dl[8], dh[8];
            #pragma unroll
            for (int n = 0; n < 8; ++n) {
                unsigned ad = bBase + ks * 16384 + n * 128;
                TR0(dl[n], ad); TR2(dh[n], ad);
            }
            asm volatile("s_waitcnt lgkmcnt(0)" ::: "memory");
            __builtin_amdgcn_sched_barrier(0);
            #pragma unroll
            for (int m = 0; m < 4; ++m)
                #pragma unroll
                for (int n = 0; n < 8; ++n) {
                    bf16x8 b = __builtin_shufflevector(dl[n], dh[n], 0, 1, 2, 3, 4, 5, 6, 7);
                    acc[m][n] = __builtin_amdgcn_mfma_f32_16x16x32_bf16(a[m], b, acc[m][n], 0, 0, 0);
                }
        }
        __syncthreads();
    }

    #pragma unroll
    for (int m = 0; m < 4; ++m) {
        int rb = wm * 64 + m * 16 + lhi * 4;
        #pragma unroll
        for (int q = 0; q < 4; ++q) {
            int r = rb + q;
            if (r < cnt) {
                int tok = rowTok[r];
                float wgt = rowW[r];
                float* orow = out + (size_t)tok * HD + h0 + wn * 128;
                #pragma unroll
                for (int n = 0; n < 8; ++n)
                    atomicAdd(&orow[n * 16 + l15], acc[m][n][q] * wgt);
            }
        }
    }
}

extern "C" void kernel_launch(void* const* d_in, const int* in_sizes, int n_in,
                              void* d_out, int out_size, void* d_ws, size_t ws_size,
                              hipStream_t stream) {
    const float* x   = (const float*)d_in[0];
    const float* wg  = (const float*)d_in[1];
    const float* wgp = (const float*)d_in[2];
    const float* wup = (const float*)d_in[3];
    const float* wdp = (const float*)d_in[4];
    float* out = (float*)d_out;

    char* ws = (char*)d_ws;
    size_t off = 0;
    unsigned short* X16   = (unsigned short*)(ws + off); off += (size_t)T_TOK * HD * 2;      // 8 MB
    unsigned short* act16 = (unsigned short*)(ws + off); off += (size_t)MAXT * 128 * ID * 2; // 31.5 MB
    int*   topk_idx   = (int*)(ws + off);   off += NPAIR * 4;
    float* topk_w     = (float*)(ws + off); off += NPAIR * 4;
    int*   token_list = (int*)(ws + off);   off += MAXT * 128 * 4;
    int*   counts     = (int*)(ws + off);   off += 256;
    int*   cursor     = (int*)(ws + off);   off += 256;
    int*   tE         = (int*)(ws + off);   off += MAXT * 4;
    int*   tStart     = (int*)(ws + off);   off += MAXT * 4;
    int*   tCnt       = (int*)(ws + off);   off += MAXT * 4;
    off = (off + 255) & ~(size_t)255;
    unsigned short* WG16 = (unsigned short*)(ws + off); off += (size_t)NE * HD * ID * 2;     // 100.7 MB
    unsigned short* WU16 = (unsigned short*)(ws + off); off += (size_t)NE * HD * ID * 2;
    unsigned short* WD16 = (unsigned short*)(ws + off); off += (size_t)NE * ID * HD * 2;
    (void)in_sizes; (void)n_in; (void)out_size; (void)ws_size;

    hipMemsetAsync(counts, 0, 256, stream);
    hipMemsetAsync(d_out, 0, (size_t)T_TOK * HD * 4, stream);

    // streaming cvt (layout-preserving) + router in one dispatch
    prep_cvt<<<PREP_GRID, 256, 0, stream>>>(x, wg, wgp, wup, wdp,
                                            X16, WG16, WU16, WD16,
                                            topk_idx, topk_w, counts);

    build_tiles<<<1, 64, 0, stream>>>(counts, cursor, tE, tStart, tCnt);
    scatter_kernel<<<NPAIR / 256, 256, 0, stream>>>(topk_idx, cursor, token_list);

    gemm1_kernel<<<MAXT * 6, 256, 0, stream>>>(X16, WG16, WU16, token_list, tE, tStart, tCnt, act16);
    gemm2_kernel<<<MAXT * 8, 256, 0, stream>>>(act16, WD16, token_list, tE, tStart, tCnt, topk_w, out);
}